// Round 1
// baseline (261.479 us; speedup 1.0000x reference)
//
#include <hip/hip_runtime.h>
#include <hip/hip_bf16.h>

#define BB 4
#define LL 1024
#define CC 768
#define HH 12
#define DD 64

typedef unsigned short ushort_t;
typedef __attribute__((ext_vector_type(8))) short bf16x8;
typedef __attribute__((ext_vector_type(4))) float f32x4;
typedef __attribute__((ext_vector_type(2))) float f32x2;

__device__ inline ushort_t f2bf(float x) {
    union { float f; unsigned u; } v; v.f = x;
    unsigned r = (v.u + 0x7FFFu + ((v.u >> 16) & 1u)) >> 16;
    return (ushort_t)r;
}
__device__ inline float u2f(unsigned u) {
    union { unsigned u; float f; } v; v.u = u;
    return v.f;
}
// pack two f32 -> packed 2xbf16 (RNE) via the HW cvt_pk path
__device__ inline unsigned pack2bf(float lo, float hi) {
    union { __hip_bfloat162 v; unsigned u; } r;
    r.v = __float22bfloat162_rn(make_float2(lo, hi));
    return r.u;
}

// Stage rows x 32 shorts from g (row stride `stride` shorts) into LDS,
// contiguous 64B rows, via async global->LDS (16B/lane, wave-uniform LDS base).
__device__ inline void stage_rows(const ushort_t* __restrict__ g, int stride,
                                  ushort_t* lds, int nbytes, int wave, int lane) {
    const int ko = (lane & 3) << 3;
    const int rsub = lane >> 2;
    for (int off = wave * 1024; off < nbytes; off += 4096) {
        int row = (off >> 6) + rsub;
        __builtin_amdgcn_global_load_lds(
            (const __attribute__((address_space(1))) void*)(g + (size_t)row * stride + ko),
            (__attribute__((address_space(3))) void*)(lds + (off >> 1)),
            16, 0, 0);
    }
}

// ---------------- prep: cast inputs + cast/transpose weights + zero Z (one launch) --------
__global__ __launch_bounds__(256) void prep(const float* __restrict__ q, const float* __restrict__ kv,
                                            const float* __restrict__ w0, const float* __restrict__ w1,
                                            const float* __restrict__ w2, const float* __restrict__ w3,
                                            ushort_t* __restrict__ qo, ushort_t* __restrict__ kvo,
                                            ushort_t* __restrict__ o0, ushort_t* __restrict__ o1,
                                            ushort_t* __restrict__ o2, ushort_t* __restrict__ o3,
                                            float* __restrict__ Zp) {
    __shared__ float t[32][33];
    const int bx = blockIdx.x;
    if (bx < 3072) {
        const float* src = bx < 1536 ? q : kv;
        ushort_t* dst = bx < 1536 ? qo : kvo;
        int bb = bx < 1536 ? bx : bx - 1536;
        size_t i = ((size_t)bb * 256 + threadIdx.x) * 8;
        float4 a = *(const float4*)(src + i);
        float4 b = *(const float4*)(src + i + 4);
        ushort_t u[8] = {f2bf(a.x), f2bf(a.y), f2bf(a.z), f2bf(a.w),
                         f2bf(b.x), f2bf(b.y), f2bf(b.z), f2bf(b.w)};
        *(uint4*)(dst + i) = *(uint4*)u;
    } else if (bx < 5376) {
        int w = bx - 3072;
        int z = w / 576, rem = w % 576;
        const float* W = z == 0 ? w0 : z == 1 ? w1 : z == 2 ? w2 : w3;
        ushort_t* Wt   = z == 0 ? o0 : z == 1 ? o1 : z == 2 ? o2 : o3;
        const int c = threadIdx.x & 31, r0 = threadIdx.x >> 5;
        const int kb = (rem / 24) * 32, nb = (rem % 24) * 32;
#pragma unroll
        for (int i = 0; i < 4; ++i)
            t[r0 + 8 * i][c] = W[(size_t)(kb + r0 + 8 * i) * CC + nb + c];
        __syncthreads();
#pragma unroll
        for (int i = 0; i < 4; ++i)
            Wt[(size_t)(nb + r0 + 8 * i) * CC + kb + c] = f2bf(t[c][r0 + 8 * i]);
    } else {
        // zero softmax denominators: 4*12*1024 floats over 192 blocks
        Zp[(bx - 5376) * 256 + threadIdx.x] = 0.f;
    }
}

// ---------------- fused Q/K/V projection (MFMA bf16), z picks target ----------------
__global__ __launch_bounds__(256) void proj_gemm(const ushort_t* __restrict__ Aq,
                                                 const ushort_t* __restrict__ Akv,
                                                 const ushort_t* __restrict__ Wqt,
                                                 const ushort_t* __restrict__ Wkt,
                                                 const ushort_t* __restrict__ Wvt,
                                                 ushort_t* __restrict__ Qo,
                                                 ushort_t* __restrict__ Ko,
                                                 ushort_t* __restrict__ Vto) {
    const int z = blockIdx.z;
    const ushort_t* A  = (z == 0) ? Aq : Akv;
    const ushort_t* Wt = (z == 0) ? Wqt : (z == 1 ? Wkt : Wvt);

    __shared__ __align__(16) ushort_t a_lds[128 * 32];
    __shared__ __align__(16) ushort_t b_lds[128 * 32];

    const int tid = threadIdx.x;
    const int bm = blockIdx.x * 128, bn = blockIdx.y * 128;
    const int wave = tid >> 6, lane = tid & 63;
    const int quad = lane >> 4, lq = lane & 15;
    const int wr = wave >> 1, wc = wave & 1;

    f32x4 acc[4][4] = {};

    for (int k0 = 0; k0 < CC; k0 += 32) {
        stage_rows(A + (size_t)bm * CC + k0, CC, a_lds, 8192, wave, lane);
        stage_rows(Wt + (size_t)bn * CC + k0, CC, b_lds, 8192, wave, lane);
        __syncthreads();
        bf16x8 af[4], bfr[4];
#pragma unroll
        for (int mi = 0; mi < 4; ++mi)
            af[mi] = *(bf16x8*)&a_lds[(wr * 64 + mi * 16 + lq) * 32 + quad * 8];
#pragma unroll
        for (int ni = 0; ni < 4; ++ni)
            bfr[ni] = *(bf16x8*)&b_lds[(wc * 64 + ni * 16 + lq) * 32 + quad * 8];
#pragma unroll
        for (int mi = 0; mi < 4; ++mi)
#pragma unroll
            for (int ni = 0; ni < 4; ++ni)
                acc[mi][ni] = __builtin_amdgcn_mfma_f32_16x16x32_bf16(af[mi], bfr[ni], acc[mi][ni], 0, 0, 0);
        __syncthreads();
    }

    const float scale = (z == 0) ? 0.125f : 1.0f;
#pragma unroll
    for (int mi = 0; mi < 4; ++mi)
#pragma unroll
        for (int ni = 0; ni < 4; ++ni)
#pragma unroll
            for (int r = 0; r < 4; ++r) {
                int row = bm + wr * 64 + mi * 16 + quad * 4 + r;  // b*1024+l
                int col = bn + wc * 64 + ni * 16 + lq;            // h*64+d
                int b = row >> 10, l = row & 1023, h = col >> 6, d = col & 63;
                ushort_t v = f2bf(acc[mi][ni][r] * scale);
                if (z == 0)      Qo[((size_t)(b * HH + h) * LL + l) * DD + d] = v;
                else if (z == 1) Ko[((size_t)(b * HH + h) * LL + l) * DD + d] = v;
                else             Vto[((size_t)(b * HH + h) * DD + d) * LL + l] = v;
            }
}

// ---------------- QK^T fused with premix + exp + denominator accumulation ----------------
// Computes S^T per 32x32 (k,l) tile for ALL 12 heads, premixes in fp32 registers,
// exponentiates, stores E = exp(premix(S)) bf16 in [b][k][l][12] layout, and
// atomically accumulates Z[b][i][l] = sum_k E from the ROUNDED bf16 values.
// S^T orientation (mfma(K,Q)) makes each thread's 4 acc rows 4 k-values of one l,
// so the denominator partial is thread-local.
__global__ __launch_bounds__(256) void qk_premix(const ushort_t* __restrict__ Q,
                                                 const ushort_t* __restrict__ K,
                                                 const float* __restrict__ Wpre,
                                                 ushort_t* __restrict__ E,
                                                 float* __restrict__ Z) {
    __shared__ __align__(16) ushort_t k_lds[2][2048];  // [buf][sub*1024 + row*32 + col]
    __shared__ __align__(16) ushort_t q_lds[2][2048];

    const int tid = threadIdx.x;
    const int bk = blockIdx.x * 32;   // k rows of S^T
    const int bl = blockIdx.y * 32;   // l cols
    const int b  = blockIdx.z;
    const int lane = tid & 63, wave = tid >> 6;
    const int quad = lane >> 4, lq = lane & 15;
    const int wr = wave >> 1, wc = wave & 1;

    // staging: thread covers 16B at linear byte o within 4KB [2 d-sub][32 row][32 col]
    const int o = tid << 4;
    const int goff = ((o >> 6) & 31) * DD + (o >> 11) * 32 + ((o >> 4) & 3) * 8;
    const ushort_t* Kbase = K + ((size_t)b * HH * LL + bk) * DD;
    const ushort_t* Qbase = Q + ((size_t)b * HH * LL + bl) * DD;

    f32x4 acc[HH] = {};

#define STAGE_QK(h, bf)                                                                             \
    do {                                                                                            \
        __builtin_amdgcn_global_load_lds(                                                           \
            (const __attribute__((address_space(1))) void*)(Kbase + (size_t)(h) * LL * DD + goff),  \
            (__attribute__((address_space(3))) void*)(&k_lds[bf][0] + (o >> 1)), 16, 0, 0);         \
        __builtin_amdgcn_global_load_lds(                                                           \
            (const __attribute__((address_space(1))) void*)(Qbase + (size_t)(h) * LL * DD + goff),  \
            (__attribute__((address_space(3))) void*)(&q_lds[bf][0] + (o >> 1)), 16, 0, 0);         \
    } while (0)

    STAGE_QK(0, 0);
    __syncthreads();
#pragma unroll
    for (int h = 0; h < HH; ++h) {
        const int buf = h & 1;
        if (h < HH - 1) STAGE_QK(h + 1, buf ^ 1);
        bf16x8 a0 = *(bf16x8*)&k_lds[buf][(wr * 16 + lq) * 32 + quad * 8];
        bf16x8 a1 = *(bf16x8*)&k_lds[buf][1024 + (wr * 16 + lq) * 32 + quad * 8];
        bf16x8 b0 = *(bf16x8*)&q_lds[buf][(wc * 16 + lq) * 32 + quad * 8];
        bf16x8 b1 = *(bf16x8*)&q_lds[buf][1024 + (wc * 16 + lq) * 32 + quad * 8];
        acc[h] = __builtin_amdgcn_mfma_f32_16x16x32_bf16(a0, b0, acc[h], 0, 0, 0);
        acc[h] = __builtin_amdgcn_mfma_f32_16x16x32_bf16(a1, b1, acc[h], 0, 0, 0);
        __syncthreads();
    }
#undef STAGE_QK

    // premix (fp32, thread-local across heads) + exp + pack bf16 pairs (heads 2i,2i+1)
    unsigned pk[6][4];
#pragma unroll
    for (int i2 = 0; i2 < 6; ++i2) {
        f32x4 m0 = {}, m1 = {};
#pragma unroll
        for (int h = 0; h < HH; ++h) {
            m0 += acc[h] * Wpre[h * HH + 2 * i2];
            m1 += acc[h] * Wpre[h * HH + 2 * i2 + 1];
        }
#pragma unroll
        for (int r = 0; r < 4; ++r)
            pk[i2][r] = pack2bf(__expf(m0[r]), __expf(m1[r]));
    }

    // denominator partials from ROUNDED values: sum this thread's 4 k-rows,
    // then reduce across quads (k groups) and atomically add per (i, l).
    float zp[HH];
#pragma unroll
    for (int i2 = 0; i2 < 6; ++i2) {
        float s0 = 0.f, s1 = 0.f;
#pragma unroll
        for (int r = 0; r < 4; ++r) {
            s0 += u2f(pk[i2][r] << 16);
            s1 += u2f(pk[i2][r] & 0xFFFF0000u);
        }
        zp[2 * i2] = s0; zp[2 * i2 + 1] = s1;
    }
#pragma unroll
    for (int i = 0; i < HH; ++i) {
        zp[i] += __shfl_xor(zp[i], 16);
        zp[i] += __shfl_xor(zp[i], 32);
    }
    if (quad == 0) {
#pragma unroll
        for (int i = 0; i < HH; ++i)
            atomicAdd(&Z[((size_t)b * HH + i) * LL + bl + wc * 16 + lq], zp[i]);
    }

    // store E[b][k][l][12]: 24B (12 heads) per (k,l) position, head-contiguous
#pragma unroll
    for (int r = 0; r < 4; ++r) {
        ushort_t* ep = E + (((size_t)b * LL + bk + wr * 16 + quad * 4 + r) * LL
                            + bl + wc * 16 + lq) * HH;
        *(uint2*)ep       = make_uint2(pk[0][r], pk[1][r]);
        *(uint2*)(ep + 4) = make_uint2(pk[2][r], pk[3][r]);
        *(uint2*)(ep + 8) = make_uint2(pk[4][r], pk[5][r]);
    }
}

// ---------------- PV fused with normalize + postmix ----------------
// Block = (b, 16 l-rows), 512 threads / 8 waves, all 12 output heads.
// Per 64-k tile: read E direct from global (once), scale by 1/Z, postmix (packed f32),
// write mixed P to XOR-swizzled LDS; stage V slice via global_load_lds with
// pre-swizzled source; MFMA O_i += P_i x V_i^T. Waves split (2 head-groups x 4 d-quads).
__global__ __launch_bounds__(512) void pv_postmix(const ushort_t* __restrict__ E,
                                                  const ushort_t* __restrict__ Vt,
                                                  const float* __restrict__ Wpost,
                                                  const float* __restrict__ Z,
                                                  ushort_t* __restrict__ att) {
    __shared__ __align__(16) ushort_t v_lds[HH * 64 * 64];  // 96KB, rows [h*64+d][64 k], swizzled
    __shared__ __align__(16) ushort_t p_lds[HH * 16 * 64];  // 24KB, rows [h*16+l][64 k], swizzled

    const int tid = threadIdx.x;
    const int bl = blockIdx.x * 16;
    const int b  = blockIdx.y;
    const int lane = tid & 63, wave = tid >> 6;
    const int quad = lane >> 4, lq = lane & 15;
    const int ig = (wave >> 2) * 6;            // head-group base (0 or 6)
    const int wd = wave & 3;                   // d-quadrant (16 cols)
    const int lmix = tid & 15, kp = tid >> 4;  // mixing role: l row, k-pair 0..31

    float invZ[HH];
#pragma unroll
    for (int h = 0; h < HH; ++h)
        invZ[h] = 1.0f / Z[((size_t)b * HH + h) * LL + bl + lmix];

    f32x4 acc[6] = {};

#pragma unroll 1
    for (int kt = 0; kt < 16; ++kt) {
        // ---- stage V slice [12][64 d][64 k] with source-side XOR swizzle (chunk ^= row&7)
#pragma unroll
        for (int j = 0; j < 12; ++j) {
            const int o = (tid << 4) + (j << 13);
            const int row = o >> 7;
            const int cs = ((o >> 4) & 7) ^ (row & 7);
            const ushort_t* src = Vt + ((size_t)b * HH * 64 + row) * LL + kt * 64 + cs * 8;
            __builtin_amdgcn_global_load_lds(
                (const __attribute__((address_space(1))) void*)src,
                (__attribute__((address_space(3))) void*)(v_lds + (o >> 1)), 16, 0, 0);
        }

        // ---- load E for 2 adjacent k at this thread's l; normalize + postmix (packed f32)
        const int kg = kt * 64 + kp * 2;
        const ushort_t* ep = E + (((size_t)b * LL + kg) * LL + bl + lmix) * HH;
        uint2 ua = *(const uint2*)ep;
        uint2 ub = *(const uint2*)(ep + 4);
        uint2 uc = *(const uint2*)(ep + 8);
        uint2 va = *(const uint2*)(ep + (size_t)LL * HH);
        uint2 vb = *(const uint2*)(ep + (size_t)LL * HH + 4);
        uint2 vc = *(const uint2*)(ep + (size_t)LL * HH + 8);
        unsigned w0[6] = {ua.x, ua.y, ub.x, ub.y, uc.x, uc.y};
        unsigned w1[6] = {va.x, va.y, vb.x, vb.y, vc.x, vc.y};

        f32x2 m[HH] = {};
#pragma unroll
        for (int h2 = 0; h2 < 6; ++h2) {
            f32x2 pe, po;
            pe.x = u2f(w0[h2] << 16);           pe.y = u2f(w1[h2] << 16);
            po.x = u2f(w0[h2] & 0xFFFF0000u);   po.y = u2f(w1[h2] & 0xFFFF0000u);
            pe *= invZ[2 * h2];
            po *= invZ[2 * h2 + 1];
#pragma unroll
            for (int i = 0; i < HH; ++i) {
                m[i] += pe * Wpost[(2 * h2) * HH + i];
                m[i] += po * Wpost[(2 * h2 + 1) * HH + i];
            }
        }
        {
            const int cs = (kp >> 2) ^ (lmix & 7);
            unsigned* pw = (unsigned*)p_lds;
#pragma unroll
            for (int i = 0; i < HH; ++i)
                pw[(i * 16 + lmix) * 32 + cs * 4 + (kp & 3)] = pack2bf(m[i].x, m[i].y);
        }
        __syncthreads();   // drains vmcnt (V staged) + lgkm (P written)

        // ---- MFMA: O_i[16 l][16 d] += P_i x V_i^T over K=64
#pragma unroll
        for (int k0 = 0; k0 < 2; ++k0)
#pragma unroll
            for (int ii = 0; ii < 6; ++ii) {
                const int hh = ig + ii;
                const int ch = ((k0 << 2) + quad) ^ (lq & 7);
                bf16x8 pa  = *(bf16x8*)&p_lds[(hh * 16 + lq) * 64 + ch * 8];
                bf16x8 vbf = *(bf16x8*)&v_lds[(hh * 64 + wd * 16 + lq) * 64 + ch * 8];
                acc[ii] = __builtin_amdgcn_mfma_f32_16x16x32_bf16(pa, vbf, acc[ii], 0, 0, 0);
            }
        __syncthreads();
    }

#pragma unroll
    for (int ii = 0; ii < 6; ++ii)
#pragma unroll
        for (int r = 0; r < 4; ++r)
            att[((size_t)b * LL + bl + quad * 4 + r) * CC + (ig + ii) * 64 + wd * 16 + lq] =
                f2bf(acc[ii][r]);
}

// ---------------- out = att @ Wout (MFMA, fp32 out). BM=128, BN=64 -> 384 blocks ----------------
__global__ __launch_bounds__(256) void out_gemm(const ushort_t* __restrict__ A,
                                                const ushort_t* __restrict__ Wt,
                                                float* __restrict__ out) {
    __shared__ __align__(16) ushort_t a_lds[128 * 32];
    __shared__ __align__(16) ushort_t b_lds[64 * 32];

    const int tid = threadIdx.x;
    const int bm = blockIdx.x * 128, bn = blockIdx.y * 64;
    const int wave = tid >> 6, lane = tid & 63;
    const int quad = lane >> 4, lq = lane & 15;
    const int wr = wave >> 1, wc = wave & 1;

    f32x4 acc[4][2] = {};

    for (int k0 = 0; k0 < CC; k0 += 32) {
        stage_rows(A + (size_t)bm * CC + k0, CC, a_lds, 8192, wave, lane);
        stage_rows(Wt + (size_t)bn * CC + k0, CC, b_lds, 4096, wave, lane);
        __syncthreads();
        bf16x8 af[4], bfr[2];
#pragma unroll
        for (int mi = 0; mi < 4; ++mi)
            af[mi] = *(bf16x8*)&a_lds[(wr * 64 + mi * 16 + lq) * 32 + quad * 8];
#pragma unroll
        for (int ni = 0; ni < 2; ++ni)
            bfr[ni] = *(bf16x8*)&b_lds[(wc * 32 + ni * 16 + lq) * 32 + quad * 8];
#pragma unroll
        for (int mi = 0; mi < 4; ++mi)
#pragma unroll
            for (int ni = 0; ni < 2; ++ni)
                acc[mi][ni] = __builtin_amdgcn_mfma_f32_16x16x32_bf16(af[mi], bfr[ni], acc[mi][ni], 0, 0, 0);
        __syncthreads();
    }

#pragma unroll
    for (int mi = 0; mi < 4; ++mi)
#pragma unroll
        for (int ni = 0; ni < 2; ++ni)
#pragma unroll
            for (int r = 0; r < 4; ++r) {
                int row = bm + wr * 64 + mi * 16 + quad * 4 + r;
                int col = bn + wc * 32 + ni * 16 + lq;
                out[(size_t)row * CC + col] = acc[mi][ni][r];
            }
}

// ---------------- Launch ----------------
extern "C" void kernel_launch(void* const* d_in, const int* in_sizes, int n_in,
                              void* d_out, int out_size, void* d_ws, size_t ws_size,
                              hipStream_t stream) {
    const float* inputs_q  = (const float*)d_in[0];
    const float* inputs_kv = (const float*)d_in[1];
    const float* Wq   = (const float*)d_in[2];
    const float* Wk   = (const float*)d_in[3];
    const float* Wv   = (const float*)d_in[4];
    const float* Wout = (const float*)d_in[5];
    const float* Wpre  = (const float*)d_in[6];
    const float* Wpost = (const float*)d_in[7];
    float* out = (float*)d_out;

    const size_t nS   = (size_t)BB * HH * LL * LL;   // E: [b][k][l][12]
    const size_t nQKV = (size_t)BB * HH * LL * DD;
    const size_t nW   = (size_t)CC * CC;

    ushort_t* Eb   = (ushort_t*)d_ws;
    ushort_t* Qb   = Eb + nS;
    ushort_t* Kb   = Qb + nQKV;
    ushort_t* Vtb  = Kb + nQKV;
    ushort_t* attb = Vtb + nQKV;
    ushort_t* inq  = attb + nQKV;
    ushort_t* inkv = inq + nQKV;
    ushort_t* Wqt  = inkv + nQKV;
    ushort_t* Wkt  = Wqt + nW;
    ushort_t* Wvt  = Wkt + nW;
    ushort_t* Wot  = Wvt + nW;
    float*    Zb   = (float*)(Wot + nW);             // [b][h][l] fp32, 192KB

    dim3 blk(256);

    prep<<<dim3(5568), blk, 0, stream>>>(inputs_q, inputs_kv, Wq, Wk, Wv, Wout,
                                         inq, inkv, Wqt, Wkt, Wvt, Wot, Zb);
    proj_gemm<<<dim3(32, 6, 3), blk, 0, stream>>>(inq, inkv, Wqt, Wkt, Wvt, Qb, Kb, Vtb);
    qk_premix<<<dim3(32, 32, BB), blk, 0, stream>>>(Qb, Kb, Wpre, Eb, Zb);
    pv_postmix<<<dim3(LL / 16, BB), dim3(512), 0, stream>>>(Eb, Vtb, Wpost, Zb, attb);
    out_gemm<<<dim3(32, 12), blk, 0, stream>>>(attb, Wot, out);
}

// Round 3
// 251.765 us; speedup vs baseline: 1.0386x; 1.0386x over previous
//
#include <hip/hip_runtime.h>
#include <hip/hip_bf16.h>

#define BB 4
#define LL 1024
#define CC 768
#define HH 12
#define DD 64

typedef unsigned short ushort_t;
typedef __attribute__((ext_vector_type(8))) short bf16x8;
typedef __attribute__((ext_vector_type(4))) float f32x4;
typedef __attribute__((ext_vector_type(2))) float f32x2;
typedef __attribute__((ext_vector_type(2))) unsigned u32x2;

__device__ inline ushort_t f2bf(float x) {
    union { float f; unsigned u; } v; v.f = x;
    unsigned r = (v.u + 0x7FFFu + ((v.u >> 16) & 1u)) >> 16;
    return (ushort_t)r;
}
__device__ inline float u2f(unsigned u) {
    union { unsigned u; float f; } v; v.u = u;
    return v.f;
}
// pack two f32 -> packed 2xbf16 (RNE) via the HW cvt_pk path
__device__ inline unsigned pack2bf(float lo, float hi) {
    union { __hip_bfloat162 v; unsigned u; } r;
    r.v = __float22bfloat162_rn(make_float2(lo, hi));
    return r.u;
}

// Stage rows x 32 shorts from g (row stride `stride` shorts) into LDS,
// contiguous 64B rows, via async global->LDS (16B/lane, wave-uniform LDS base).
__device__ inline void stage_rows(const ushort_t* __restrict__ g, int stride,
                                  ushort_t* lds, int nbytes, int wave, int lane) {
    const int ko = (lane & 3) << 3;
    const int rsub = lane >> 2;
    for (int off = wave * 1024; off < nbytes; off += 4096) {
        int row = (off >> 6) + rsub;
        __builtin_amdgcn_global_load_lds(
            (const __attribute__((address_space(1))) void*)(g + (size_t)row * stride + ko),
            (__attribute__((address_space(3))) void*)(lds + (off >> 1)),
            16, 0, 0);
    }
}

// ---------------- prep: cast inputs + cast/transpose weights + zero Z (one launch) --------
__global__ __launch_bounds__(256) void prep(const float* __restrict__ q, const float* __restrict__ kv,
                                            const float* __restrict__ w0, const float* __restrict__ w1,
                                            const float* __restrict__ w2, const float* __restrict__ w3,
                                            ushort_t* __restrict__ qo, ushort_t* __restrict__ kvo,
                                            ushort_t* __restrict__ o0, ushort_t* __restrict__ o1,
                                            ushort_t* __restrict__ o2, ushort_t* __restrict__ o3,
                                            float* __restrict__ Zp) {
    __shared__ float t[32][33];
    const int bx = blockIdx.x;
    if (bx < 3072) {
        const float* src = bx < 1536 ? q : kv;
        ushort_t* dst = bx < 1536 ? qo : kvo;
        int bb = bx < 1536 ? bx : bx - 1536;
        size_t i = ((size_t)bb * 256 + threadIdx.x) * 8;
        float4 a = *(const float4*)(src + i);
        float4 b = *(const float4*)(src + i + 4);
        ushort_t u[8] = {f2bf(a.x), f2bf(a.y), f2bf(a.z), f2bf(a.w),
                         f2bf(b.x), f2bf(b.y), f2bf(b.z), f2bf(b.w)};
        *(uint4*)(dst + i) = *(uint4*)u;
    } else if (bx < 5376) {
        int w = bx - 3072;
        int z = w / 576, rem = w % 576;
        const float* W = z == 0 ? w0 : z == 1 ? w1 : z == 2 ? w2 : w3;
        ushort_t* Wt   = z == 0 ? o0 : z == 1 ? o1 : z == 2 ? o2 : o3;
        const int c = threadIdx.x & 31, r0 = threadIdx.x >> 5;
        const int kb = (rem / 24) * 32, nb = (rem % 24) * 32;
#pragma unroll
        for (int i = 0; i < 4; ++i)
            t[r0 + 8 * i][c] = W[(size_t)(kb + r0 + 8 * i) * CC + nb + c];
        __syncthreads();
#pragma unroll
        for (int i = 0; i < 4; ++i)
            Wt[(size_t)(nb + r0 + 8 * i) * CC + kb + c] = f2bf(t[c][r0 + 8 * i]);
    } else {
        // zero softmax denominators: 4*12*1024 floats over 192 blocks
        Zp[(bx - 5376) * 256 + threadIdx.x] = 0.f;
    }
}

// ---------------- fused Q/K/V projection (MFMA bf16), z picks target ----------------
// Q and K are written PRE-TILED in MFMA-fragment order:
//   per (b,h) plane of 64K elems: off = ((l>>4)*8 + (d>>3))*128 + (l&15)*8 + (d&7)
// so qk_premix can load fragments as contiguous 1KB wave-reads with no LDS.
__global__ __launch_bounds__(256) void proj_gemm(const ushort_t* __restrict__ Aq,
                                                 const ushort_t* __restrict__ Akv,
                                                 const ushort_t* __restrict__ Wqt,
                                                 const ushort_t* __restrict__ Wkt,
                                                 const ushort_t* __restrict__ Wvt,
                                                 ushort_t* __restrict__ Qo,
                                                 ushort_t* __restrict__ Ko,
                                                 ushort_t* __restrict__ Vto) {
    const int z = blockIdx.z;
    const ushort_t* A  = (z == 0) ? Aq : Akv;
    const ushort_t* Wt = (z == 0) ? Wqt : (z == 1 ? Wkt : Wvt);

    __shared__ __align__(16) ushort_t a_lds[128 * 32];
    __shared__ __align__(16) ushort_t b_lds[128 * 32];

    const int tid = threadIdx.x;
    const int bm = blockIdx.x * 128, bn = blockIdx.y * 128;
    const int wave = tid >> 6, lane = tid & 63;
    const int quad = lane >> 4, lq = lane & 15;
    const int wr = wave >> 1, wc = wave & 1;

    f32x4 acc[4][4] = {};

    for (int k0 = 0; k0 < CC; k0 += 32) {
        stage_rows(A + (size_t)bm * CC + k0, CC, a_lds, 8192, wave, lane);
        stage_rows(Wt + (size_t)bn * CC + k0, CC, b_lds, 8192, wave, lane);
        __syncthreads();
        bf16x8 af[4], bfr[4];
#pragma unroll
        for (int mi = 0; mi < 4; ++mi)
            af[mi] = *(bf16x8*)&a_lds[(wr * 64 + mi * 16 + lq) * 32 + quad * 8];
#pragma unroll
        for (int ni = 0; ni < 4; ++ni)
            bfr[ni] = *(bf16x8*)&b_lds[(wc * 64 + ni * 16 + lq) * 32 + quad * 8];
#pragma unroll
        for (int mi = 0; mi < 4; ++mi)
#pragma unroll
            for (int ni = 0; ni < 4; ++ni)
                acc[mi][ni] = __builtin_amdgcn_mfma_f32_16x16x32_bf16(af[mi], bfr[ni], acc[mi][ni], 0, 0, 0);
        __syncthreads();
    }

    const float scale = (z == 0) ? 0.125f : 1.0f;
#pragma unroll
    for (int mi = 0; mi < 4; ++mi)
#pragma unroll
        for (int ni = 0; ni < 4; ++ni)
#pragma unroll
            for (int r = 0; r < 4; ++r) {
                int row = bm + wr * 64 + mi * 16 + quad * 4 + r;  // b*1024 + l(or k)
                int col = bn + wc * 64 + ni * 16 + lq;            // h*64 + d
                int b = row >> 10, l = row & 1023, h = col >> 6, d = col & 63;
                ushort_t v = f2bf(acc[mi][ni][r] * scale);
                if (z == 2) {
                    Vto[((size_t)(b * HH + h) * DD + d) * LL + l] = v;
                } else {
                    size_t off = (size_t)(b * HH + h) * (LL * DD)
                               + (size_t)(((l >> 4) * 8 + (d >> 3)) * 128 + (l & 15) * 8 + (d & 7));
                    if (z == 0) Qo[off] = v;
                    else        Ko[off] = v;
                }
            }
}

// ---------------- QK^T fused with premix + exp + denominator accumulation ----------------
// Barrier-free, LDS-free: Q/K arrive pre-tiled in fragment order, so each wave's
// MFMA operands are contiguous 1KB global loads (served from L2: blockIdx is
// swizzled so each XCD-pair owns one batch b, K+Q per b = 3MB < 4MB L2).
// Per block: 32x32 (k,l) tile, all 12 heads in fp32 acc; premix thread-local;
// E = exp(premix(S^T)) stored bf16 [b][k][l][12] via nontemporal stores (keeps
// the streaming 96MB write from evicting Q/K out of L2).
__global__ __launch_bounds__(256) void qk_premix(const ushort_t* __restrict__ Qf,
                                                 const ushort_t* __restrict__ Kf,
                                                 const float* __restrict__ Wpre,
                                                 ushort_t* __restrict__ E,
                                                 float* __restrict__ Z) {
    const int tid = threadIdx.x;
    const int lane = tid & 63, wave = tid >> 6;
    const int quad = lane >> 4, lq = lane & 15;
    const int wr = wave >> 1, wc = wave & 1;

    // XCD-aware decode: xcd = x%8 (round-robin dispatch); each XCD-pair owns one b.
    const int x = blockIdx.x;
    const int xcd = x & 7;
    const int b = xcd >> 1;                           // 0..3
    const int s = x >> 3;                             // 0..511
    const int bk = (s & 31) << 5;                     // k-tile base
    const int bl = ((((s >> 5) << 1) | (xcd & 1))) << 5;  // l-tile base

    // fragment bases: per (b,h) plane LL*DD elems; k16-block = 1024 elems (2KB)
    const ushort_t* Kp = Kf + (size_t)b * HH * LL * DD
                       + (size_t)(((bk >> 4) + wr) * 1024 + quad * 128 + lq * 8);
    const ushort_t* Qp = Qf + (size_t)b * HH * LL * DD
                       + (size_t)(((bl >> 4) + wc) * 1024 + quad * 128 + lq * 8);

    f32x4 acc[HH] = {};
#pragma unroll
    for (int h = 0; h < HH; ++h) {
        const size_t ho = (size_t)h * (LL * DD);
        bf16x8 ka0 = *(const bf16x8*)(Kp + ho);
        bf16x8 ka1 = *(const bf16x8*)(Kp + ho + 512);
        bf16x8 qb0 = *(const bf16x8*)(Qp + ho);
        bf16x8 qb1 = *(const bf16x8*)(Qp + ho + 512);
        acc[h] = __builtin_amdgcn_mfma_f32_16x16x32_bf16(ka0, qb0, acc[h], 0, 0, 0);
        acc[h] = __builtin_amdgcn_mfma_f32_16x16x32_bf16(ka1, qb1, acc[h], 0, 0, 0);
    }

    // premix (fp32, thread-local across heads) + exp + pack bf16 pairs (heads 2i,2i+1)
    unsigned pk[6][4];
#pragma unroll
    for (int i2 = 0; i2 < 6; ++i2) {
        f32x4 m0 = {}, m1 = {};
#pragma unroll
        for (int h = 0; h < HH; ++h) {
            m0 += acc[h] * Wpre[h * HH + 2 * i2];
            m1 += acc[h] * Wpre[h * HH + 2 * i2 + 1];
        }
#pragma unroll
        for (int r = 0; r < 4; ++r)
            pk[i2][r] = pack2bf(__expf(m0[r]), __expf(m1[r]));
    }

    // denominator partials from ROUNDED values: sum this thread's 4 k-rows,
    // reduce across quads (k groups), atomically add per (i, l).
    float zp[HH];
#pragma unroll
    for (int i2 = 0; i2 < 6; ++i2) {
        float s0 = 0.f, s1 = 0.f;
#pragma unroll
        for (int r = 0; r < 4; ++r) {
            s0 += u2f(pk[i2][r] << 16);
            s1 += u2f(pk[i2][r] & 0xFFFF0000u);
        }
        zp[2 * i2] = s0; zp[2 * i2 + 1] = s1;
    }
#pragma unroll
    for (int i = 0; i < HH; ++i) {
        zp[i] += __shfl_xor(zp[i], 16);
        zp[i] += __shfl_xor(zp[i], 32);
    }
    if (quad == 0) {
#pragma unroll
        for (int i = 0; i < HH; ++i)
            atomicAdd(&Z[((size_t)b * HH + i) * LL + bl + wc * 16 + lq], zp[i]);
    }

    // store E[b][k][l][12]: 24B (12 heads) per (k,l) position, head-contiguous, NT
#pragma unroll
    for (int r = 0; r < 4; ++r) {
        ushort_t* ep = E + (((size_t)b * LL + bk + wr * 16 + quad * 4 + r) * LL
                            + bl + wc * 16 + lq) * HH;
        u32x2 s0; s0.x = pk[0][r]; s0.y = pk[1][r];
        u32x2 s1; s1.x = pk[2][r]; s1.y = pk[3][r];
        u32x2 s2; s2.x = pk[4][r]; s2.y = pk[5][r];
        __builtin_nontemporal_store(s0, (u32x2*)ep);
        __builtin_nontemporal_store(s1, (u32x2*)(ep + 4));
        __builtin_nontemporal_store(s2, (u32x2*)(ep + 8));
    }
}

// ---------------- PV fused with normalize + postmix ----------------
// Block = (b, 16 l-rows), 512 threads / 8 waves, all 12 output heads.
// Per 64-k tile: read E direct from global (once, nontemporal), scale by 1/Z,
// postmix (packed f32), write mixed P to XOR-swizzled LDS; stage V slice via
// global_load_lds with pre-swizzled source; MFMA O_i += P_i x V_i^T.
__global__ __launch_bounds__(512) void pv_postmix(const ushort_t* __restrict__ E,
                                                  const ushort_t* __restrict__ Vt,
                                                  const float* __restrict__ Wpost,
                                                  const float* __restrict__ Z,
                                                  ushort_t* __restrict__ att) {
    __shared__ __align__(16) ushort_t v_lds[HH * 64 * 64];  // 96KB, rows [h*64+d][64 k], swizzled
    __shared__ __align__(16) ushort_t p_lds[HH * 16 * 64];  // 24KB, rows [h*16+l][64 k], swizzled

    const int tid = threadIdx.x;
    const int bl = blockIdx.x * 16;
    const int b  = blockIdx.y;
    const int lane = tid & 63, wave = tid >> 6;
    const int quad = lane >> 4, lq = lane & 15;
    const int ig = (wave >> 2) * 6;            // head-group base (0 or 6)
    const int wd = wave & 3;                   // d-quadrant (16 cols)
    const int lmix = tid & 15, kp = tid >> 4;  // mixing role: l row, k-pair 0..31

    float invZ[HH];
#pragma unroll
    for (int h = 0; h < HH; ++h)
        invZ[h] = 1.0f / Z[((size_t)b * HH + h) * LL + bl + lmix];

    f32x4 acc[6] = {};

#pragma unroll 1
    for (int kt = 0; kt < 16; ++kt) {
        // ---- stage V slice [12][64 d][64 k] with source-side XOR swizzle (chunk ^= row&7)
#pragma unroll
        for (int j = 0; j < 12; ++j) {
            const int o = (tid << 4) + (j << 13);
            const int row = o >> 7;
            const int cs = ((o >> 4) & 7) ^ (row & 7);
            const ushort_t* src = Vt + ((size_t)b * HH * 64 + row) * LL + kt * 64 + cs * 8;
            __builtin_amdgcn_global_load_lds(
                (const __attribute__((address_space(1))) void*)src,
                (__attribute__((address_space(3))) void*)(v_lds + (o >> 1)), 16, 0, 0);
        }

        // ---- load E for 2 adjacent k at this thread's l; normalize + postmix (packed f32)
        const int kg = kt * 64 + kp * 2;
        const ushort_t* ep = E + (((size_t)b * LL + kg) * LL + bl + lmix) * HH;
        u32x2 ua = __builtin_nontemporal_load((const u32x2*)ep);
        u32x2 ub = __builtin_nontemporal_load((const u32x2*)(ep + 4));
        u32x2 uc = __builtin_nontemporal_load((const u32x2*)(ep + 8));
        u32x2 va = __builtin_nontemporal_load((const u32x2*)(ep + (size_t)LL * HH));
        u32x2 vb = __builtin_nontemporal_load((const u32x2*)(ep + (size_t)LL * HH + 4));
        u32x2 vc = __builtin_nontemporal_load((const u32x2*)(ep + (size_t)LL * HH + 8));
        unsigned w0[6] = {ua.x, ua.y, ub.x, ub.y, uc.x, uc.y};
        unsigned w1[6] = {va.x, va.y, vb.x, vb.y, vc.x, vc.y};

        f32x2 m[HH] = {};
#pragma unroll
        for (int h2 = 0; h2 < 6; ++h2) {
            f32x2 pe, po;
            pe.x = u2f(w0[h2] << 16);           pe.y = u2f(w1[h2] << 16);
            po.x = u2f(w0[h2] & 0xFFFF0000u);   po.y = u2f(w1[h2] & 0xFFFF0000u);
            pe *= invZ[2 * h2];
            po *= invZ[2 * h2 + 1];
#pragma unroll
            for (int i = 0; i < HH; ++i) {
                m[i] += pe * Wpost[(2 * h2) * HH + i];
                m[i] += po * Wpost[(2 * h2 + 1) * HH + i];
            }
        }
        {
            const int cs = (kp >> 2) ^ (lmix & 7);
            unsigned* pw = (unsigned*)p_lds;
#pragma unroll
            for (int i = 0; i < HH; ++i)
                pw[(i * 16 + lmix) * 32 + cs * 4 + (kp & 3)] = pack2bf(m[i].x, m[i].y);
        }
        __syncthreads();   // drains vmcnt (V staged) + lgkm (P written)

        // ---- MFMA: O_i[16 l][16 d] += P_i x V_i^T over K=64
#pragma unroll
        for (int k0 = 0; k0 < 2; ++k0)
#pragma unroll
            for (int ii = 0; ii < 6; ++ii) {
                const int hh = ig + ii;
                const int ch = ((k0 << 2) + quad) ^ (lq & 7);
                bf16x8 pa  = *(bf16x8*)&p_lds[(hh * 16 + lq) * 64 + ch * 8];
                bf16x8 vbf = *(bf16x8*)&v_lds[(hh * 64 + wd * 16 + lq) * 64 + ch * 8];
                acc[ii] = __builtin_amdgcn_mfma_f32_16x16x32_bf16(pa, vbf, acc[ii], 0, 0, 0);
            }
        __syncthreads();
    }

#pragma unroll
    for (int ii = 0; ii < 6; ++ii)
#pragma unroll
        for (int r = 0; r < 4; ++r)
            att[((size_t)b * LL + bl + quad * 4 + r) * CC + (ig + ii) * 64 + wd * 16 + lq] =
                f2bf(acc[ii][r]);
}

// ---------------- out = att @ Wout (MFMA, fp32 out). BM=128, BN=64 -> 384 blocks ----------------
__global__ __launch_bounds__(256) void out_gemm(const ushort_t* __restrict__ A,
                                                const ushort_t* __restrict__ Wt,
                                                float* __restrict__ out) {
    __shared__ __align__(16) ushort_t a_lds[128 * 32];
    __shared__ __align__(16) ushort_t b_lds[64 * 32];

    const int tid = threadIdx.x;
    const int bm = blockIdx.x * 128, bn = blockIdx.y * 64;
    const int wave = tid >> 6, lane = tid & 63;
    const int quad = lane >> 4, lq = lane & 15;
    const int wr = wave >> 1, wc = wave & 1;

    f32x4 acc[4][2] = {};

    for (int k0 = 0; k0 < CC; k0 += 32) {
        stage_rows(A + (size_t)bm * CC + k0, CC, a_lds, 8192, wave, lane);
        stage_rows(Wt + (size_t)bn * CC + k0, CC, b_lds, 4096, wave, lane);
        __syncthreads();
        bf16x8 af[4], bfr[2];
#pragma unroll
        for (int mi = 0; mi < 4; ++mi)
            af[mi] = *(bf16x8*)&a_lds[(wr * 64 + mi * 16 + lq) * 32 + quad * 8];
#pragma unroll
        for (int ni = 0; ni < 2; ++ni)
            bfr[ni] = *(bf16x8*)&b_lds[(wc * 32 + ni * 16 + lq) * 32 + quad * 8];
#pragma unroll
        for (int mi = 0; mi < 4; ++mi)
#pragma unroll
            for (int ni = 0; ni < 2; ++ni)
                acc[mi][ni] = __builtin_amdgcn_mfma_f32_16x16x32_bf16(af[mi], bfr[ni], acc[mi][ni], 0, 0, 0);
        __syncthreads();
    }

#pragma unroll
    for (int mi = 0; mi < 4; ++mi)
#pragma unroll
        for (int ni = 0; ni < 2; ++ni)
#pragma unroll
            for (int r = 0; r < 4; ++r) {
                int row = bm + wr * 64 + mi * 16 + quad * 4 + r;
                int col = bn + wc * 32 + ni * 16 + lq;
                out[(size_t)row * CC + col] = acc[mi][ni][r];
            }
}

// ---------------- Launch ----------------
extern "C" void kernel_launch(void* const* d_in, const int* in_sizes, int n_in,
                              void* d_out, int out_size, void* d_ws, size_t ws_size,
                              hipStream_t stream) {
    const float* inputs_q  = (const float*)d_in[0];
    const float* inputs_kv = (const float*)d_in[1];
    const float* Wq   = (const float*)d_in[2];
    const float* Wk   = (const float*)d_in[3];
    const float* Wv   = (const float*)d_in[4];
    const float* Wout = (const float*)d_in[5];
    const float* Wpre  = (const float*)d_in[6];
    const float* Wpost = (const float*)d_in[7];
    float* out = (float*)d_out;

    const size_t nS   = (size_t)BB * HH * LL * LL;   // E: [b][k][l][12]
    const size_t nQKV = (size_t)BB * HH * LL * DD;
    const size_t nW   = (size_t)CC * CC;

    ushort_t* Eb   = (ushort_t*)d_ws;
    ushort_t* Qb   = Eb + nS;
    ushort_t* Kb   = Qb + nQKV;
    ushort_t* Vtb  = Kb + nQKV;
    ushort_t* attb = Vtb + nQKV;
    ushort_t* inq  = attb + nQKV;
    ushort_t* inkv = inq + nQKV;
    ushort_t* Wqt  = inkv + nQKV;
    ushort_t* Wkt  = Wqt + nW;
    ushort_t* Wvt  = Wkt + nW;
    ushort_t* Wot  = Wvt + nW;
    float*    Zb   = (float*)(Wot + nW);             // [b][h][l] fp32, 192KB

    dim3 blk(256);

    prep<<<dim3(5568), blk, 0, stream>>>(inputs_q, inputs_kv, Wq, Wk, Wv, Wout,
                                         inq, inkv, Wqt, Wkt, Wvt, Wot, Zb);
    proj_gemm<<<dim3(32, 6, 3), blk, 0, stream>>>(inq, inkv, Wqt, Wkt, Wvt, Qb, Kb, Vtb);
    qk_premix<<<dim3(4096), blk, 0, stream>>>(Qb, Kb, Wpre, Eb, Zb);
    pv_postmix<<<dim3(LL / 16, BB), dim3(512), 0, stream>>>(Eb, Vtb, Wpost, Zb, attb);
    out_gemm<<<dim3(32, 12), blk, 0, stream>>>(attb, Wot, out);
}